// Round 4
// baseline (518.378 us; speedup 1.0000x reference)
//
#include <hip/hip_runtime.h>
#include <hip/hip_bf16.h>
#include <stdint.h>

#define NB 50000     // batch rows
#define KN 32        // neighbors
#define NN 200000    // nodes
#define DD 256       // feature dim
#define EE 256       // embed dim

typedef unsigned short u16;
typedef __attribute__((ext_vector_type(8))) short bf16x8;
typedef __attribute__((ext_vector_type(4))) float f32x4;

static __device__ __forceinline__ u16 f2bf(float f) {
  __hip_bfloat16 h = __float2bfloat16(f);
  return *reinterpret_cast<u16*>(&h);
}
static __device__ __forceinline__ float blo(unsigned u) {
  return __uint_as_float(u << 16);
}
static __device__ __forceinline__ float bhi(unsigned u) {
  return __uint_as_float(u & 0xffff0000u);
}

// ---------------- kernel 1: Wc = W_init @ Wf_top (f32), bc = b_init @ Wf_top + b_final
__global__ void wc_kernel(const float* __restrict__ Wi, const float* __restrict__ bi,
                          const float* __restrict__ Wf, const float* __restrict__ bf,
                          float* __restrict__ Wc, float* __restrict__ bc) {
  const int e = threadIdx.x;
  const int d = blockIdx.x;
  if (d < DD) {
    const float* wrow = Wi + (size_t)d * DD;
    float acc = 0.f;
    for (int t = 0; t < DD; ++t)
      acc = fmaf(wrow[t], Wf[(size_t)t * EE + e], acc);
    Wc[(size_t)d * EE + e] = acc;
  } else {
    float acc = bf[e];
    for (int t = 0; t < DD; ++t)
      acc = fmaf(bi[t], Wf[(size_t)t * EE + e], acc);
    bc[e] = acc;
  }
}

// ---------------- kernel 2: Bt[e][0..511] bf16 = [Wc[:,e] | Wf_bot[:,e]]
__global__ void wt_kernel(const float* __restrict__ Wc, const float* __restrict__ Wf,
                          u16* __restrict__ Bt) {
  const int e = blockIdx.x, d = threadIdx.x;
  Bt[(size_t)e * 512 + d]       = f2bf(Wc[(size_t)d * EE + e]);
  Bt[(size_t)e * 512 + 256 + d] = f2bf(Wf[(size_t)(DD + d) * EE + e]);
}

// ---------------- kernel 3: features f32 -> bf16
__global__ void cvt_kernel(const float* __restrict__ in, u16* __restrict__ out, int n4) {
  int i = blockIdx.x * blockDim.x + threadIdx.x;
  const int stride = gridDim.x * blockDim.x;
  for (; i < n4; i += stride) {
    float4 v = ((const float4*)in)[i];
    ushort4 o;
    o.x = f2bf(v.x); o.y = f2bf(v.y); o.z = f2bf(v.z); o.w = f2bf(v.w);
    ((ushort4*)out)[i] = o;
  }
}

// ---------------- kernel 4: fused gather + GEMM + swish
// Block: 512 threads (8 waves), BM=64 rows, N=256 full width, K=512.
// Phase 1: wave wv gathers combined rows (self | weighted-mean neigh) for rows
//          wv*8..wv*8+7 into LDS A-tile [64][512] bf16, 16B-slot XOR swizzle
//          slot' = slot ^ (row&7) (T2: breaks the 1024B-row-stride bank wall).
// Phase 2: 2(m)x4(n) waves, wave tile 32x64; A frags from LDS, B frags direct
//          from L2-resident Bt; 8 MFMA per BK=32 step; swish epilogue.
#define BMF 64

__global__ __launch_bounds__(512, 4) void fused_kernel(const int* __restrict__ nodes,
                                                       const int* __restrict__ nidx,
                                                       const float* __restrict__ nw,
                                                       const u16* __restrict__ fb,
                                                       const u16* __restrict__ Bt,
                                                       const float* __restrict__ bc,
                                                       float* __restrict__ out, int M) {
  __shared__ u16 sA[BMF * 512];
  const int tid = threadIdx.x;
  const int l = tid & 63, wv = tid >> 6;
  const int m0 = blockIdx.x * BMF;
  const int h = l >> 5, j = l & 31;   // half-wave, half-lane

  // ---------- phase 1: gather 8 rows per wave ----------
  for (int rr = 0; rr < 8; ++rr) {
    const int r = wv * 8 + rr;
    int b = m0 + r; if (b >= M) b = M - 1;

    int   idxv = 0; float wgt = 0.f;
    if (l < KN) {
      idxv = nidx[(size_t)b * KN + l];
      wgt  = nw[(size_t)b * KN + l];
    }
    float s = wgt;
    #pragma unroll
    for (int off = 32; off >= 1; off >>= 1) s += __shfl_xor(s, off);
    const float inv = 1.f / s;

    float a[8];
    #pragma unroll
    for (int i = 0; i < 8; ++i) a[i] = 0.f;

    // 16 paired loads: lanes 0-31 do even k, lanes 32-63 odd k; 16B/lane.
    #pragma unroll
    for (int kp = 0; kp < 16; ++kp) {
      const int   ik0 = __builtin_amdgcn_readlane(idxv, 2 * kp);
      const int   ik1 = __builtin_amdgcn_readlane(idxv, 2 * kp + 1);
      const float w0  = __uint_as_float(__builtin_amdgcn_readlane(__float_as_uint(wgt), 2 * kp)) * inv;
      const float w1  = __uint_as_float(__builtin_amdgcn_readlane(__float_as_uint(wgt), 2 * kp + 1)) * inv;
      const int   ik  = h ? ik1 : ik0;
      const float wk  = h ? w1 : w0;
      const uint4 v = *(const uint4*)(fb + (size_t)ik * DD + j * 8);
      a[0] = fmaf(wk, blo(v.x), a[0]); a[1] = fmaf(wk, bhi(v.x), a[1]);
      a[2] = fmaf(wk, blo(v.y), a[2]); a[3] = fmaf(wk, bhi(v.y), a[3]);
      a[4] = fmaf(wk, blo(v.z), a[4]); a[5] = fmaf(wk, bhi(v.z), a[5]);
      a[6] = fmaf(wk, blo(v.w), a[6]); a[7] = fmaf(wk, bhi(v.w), a[7]);
    }
    // combine the two halves (lane i and i+32 hold same d-range)
    #pragma unroll
    for (int i = 0; i < 8; ++i) a[i] += __shfl_xor(a[i], 32);

    const int swz = r & 7;
    // neigh half: u16 positions 256..511 = slots 32..63; lanes 0-31 write 16B
    if (l < 32) {
      uint4 p;
      p.x = (unsigned)f2bf(a[0]) | ((unsigned)f2bf(a[1]) << 16);
      p.y = (unsigned)f2bf(a[2]) | ((unsigned)f2bf(a[3]) << 16);
      p.z = (unsigned)f2bf(a[4]) | ((unsigned)f2bf(a[5]) << 16);
      p.w = (unsigned)f2bf(a[6]) | ((unsigned)f2bf(a[7]) << 16);
      *(uint4*)&sA[r * 512 + (((32 + j) ^ swz) * 8)] = p;
    }
    // self half: raw bf16 bits, 64 lanes x 8B, slots 0..31
    const int node = nodes[b];
    const ushort4 sv = *(const ushort4*)(fb + (size_t)node * DD + l * 4);
    *(ushort4*)&sA[r * 512 + (((l >> 1) ^ swz) * 8) + (l & 1) * 4] = sv;
  }
  __syncthreads();

  // ---------- phase 2: GEMM ----------
  const int wm = wv >> 2, wn = wv & 3;
  const int fr = l & 15, kc = l >> 4;     // fragment row, k-chunk 0..3

  f32x4 acc[2][4];
  #pragma unroll
  for (int i = 0; i < 2; ++i)
    #pragma unroll
    for (int jn = 0; jn < 4; ++jn) acc[i][jn] = (f32x4){0.f, 0.f, 0.f, 0.f};

  const u16* bbase = Bt + (size_t)(wn * 64 + fr) * 512 + kc * 8;

  for (int k0 = 0; k0 < 512; k0 += 32) {
    bf16x8 af[2], bq[4];
    #pragma unroll
    for (int mf = 0; mf < 2; ++mf) {
      const int r = wm * 32 + mf * 16 + fr;
      const int slot = ((k0 >> 3) + kc) ^ (r & 7);
      af[mf] = *(const bf16x8*)&sA[r * 512 + slot * 8];
    }
    #pragma unroll
    for (int nf = 0; nf < 4; ++nf)
      bq[nf] = *(const bf16x8*)(bbase + (size_t)nf * 16 * 512 + k0);
    #pragma unroll
    for (int mf = 0; mf < 2; ++mf)
      #pragma unroll
      for (int nf = 0; nf < 4; ++nf)
        acc[mf][nf] = __builtin_amdgcn_mfma_f32_16x16x32_bf16(af[mf], bq[nf], acc[mf][nf], 0, 0, 0);
  }

  // epilogue: C/D layout col = lane&15, row = (lane>>4)*4 + i
  const int fcol = l & 15;
  const int frq = (l >> 4) * 4;
  #pragma unroll
  for (int nf = 0; nf < 4; ++nf) {
    const int col = wn * 64 + nf * 16 + fcol;
    const float bias = bc[col];
    #pragma unroll
    for (int mf = 0; mf < 2; ++mf) {
      const int rowb = m0 + wm * 32 + mf * 16 + frq;
      #pragma unroll
      for (int i = 0; i < 4; ++i) {
        const int row = rowb + i;
        if (row < M) {
          const float z = acc[mf][nf][i] + bias;
          out[(size_t)row * EE + col] = z * (1.f / (1.f + __expf(-z)));
        }
      }
    }
  }
}

extern "C" void kernel_launch(void* const* d_in, const int* in_sizes, int n_in,
                              void* d_out, int out_size, void* d_ws, size_t ws_size,
                              hipStream_t stream) {
  const int*   nodes = (const int*)d_in[0];
  const int*   nidx  = (const int*)d_in[1];
  const float* nw    = (const float*)d_in[2];
  const float* feat  = (const float*)d_in[3];
  const float* Wi    = (const float*)d_in[4];
  const float* bi    = (const float*)d_in[5];
  const float* Wf    = (const float*)d_in[6];
  const float* bf    = (const float*)d_in[7];
  float* out = (float*)d_out;

  char* ws = (char*)d_ws;
  const size_t OFF_WC = 0;          // 256*256*4 = 262,144
  const size_t OFF_BC = 262144;     // 1,024
  const size_t OFF_BT = 263168;     // 256*512*2 = 262,144
  const size_t OFF_FB = 525312;     // NN*DD*2 = 102,400,000

  float* Wc = (float*)(ws + OFF_WC);
  float* bc = (float*)(ws + OFF_BC);
  u16*   Bt = (u16*)(ws + OFF_BT);
  u16*   fb = (u16*)(ws + OFF_FB);

  wc_kernel<<<DD + 1, 256, 0, stream>>>(Wi, bi, Wf, bf, Wc, bc);
  wt_kernel<<<EE, 256, 0, stream>>>(Wc, Wf, Bt);
  cvt_kernel<<<2048, 256, 0, stream>>>(feat, fb, NN * DD / 4);

  const int blocks = (NB + BMF - 1) / BMF;   // 782
  fused_kernel<<<blocks, 512, 0, stream>>>(nodes, nidx, nw, fb, Bt, bc, out, NB);
}